// Round 12
// baseline (502.709 us; speedup 1.0000x reference)
//
#include <hip/hip_runtime.h>

#define NN 100000
#define NE 1600000
#define SD 128
#define HD 32
#define NCH 4          // feature chunks
#define CW 8           // chunk width (floats) -> 32B rows, 3.2MB/slice
#define NBK 391        // buckets of 256 nodes: ceil(100000/256)
#define EPB 4000       // edges per block in P1/P3
#define NBLK 400       // NBLK*EPB == NE exactly
#define MAXBE 6144     // max edges per bucket (mean 4096, sd 64)

// ---------- P1: per-block bucket histogram + global reservation ----------
__global__ __launch_bounds__(256) void k_p1(const int* __restrict__ dst,
                                            unsigned* __restrict__ bktcnt,
                                            unsigned* __restrict__ blockbase) {
    __shared__ unsigned h[NBK];
    int blk = blockIdx.x, tid = threadIdx.x;
    for (int i = tid; i < NBK; i += 256) h[i] = 0;
    __syncthreads();
    int e0 = blk * EPB;
    for (int i = tid; i < EPB; i += 256)
        atomicAdd(&h[(unsigned)dst[e0 + i] >> 8], 1u);
    __syncthreads();
    for (int i = tid; i < NBK; i += 256)
        blockbase[blk * NBK + i] = atomicAdd(&bktcnt[i], h[i]);   // 156K atomics total
}

// ---------- P2: scan bucket totals -> bucket bases ----------
__global__ __launch_bounds__(512) void k_p2(const unsigned* __restrict__ bktcnt,
                                            unsigned* __restrict__ bktbase,
                                            unsigned* __restrict__ rowptr) {
    __shared__ unsigned sc[512];
    int tid = threadIdx.x;
    unsigned c = (tid < NBK) ? bktcnt[tid] : 0u;
    sc[tid] = c;
    __syncthreads();
    for (int off = 1; off < 512; off <<= 1) {
        unsigned t = (tid >= off) ? sc[tid - off] : 0u;
        __syncthreads();
        sc[tid] += t;
        __syncthreads();
    }
    if (tid <= NBK) bktbase[tid] = sc[tid] - c;    // exclusive; bktbase[NBK] == NE
    if (tid == 0) rowptr[NN] = NE;
}

// ---------- P3: scatter edges into buckets (block-contiguous chunks) ----------
__global__ __launch_bounds__(256) void k_p3(const int* __restrict__ src,
                                            const int* __restrict__ dst,
                                            const unsigned* __restrict__ bktbase,
                                            const unsigned* __restrict__ blockbase,
                                            unsigned* __restrict__ ebuf) {
    __shared__ unsigned cur[NBK];
    int blk = blockIdx.x, tid = threadIdx.x;
    for (int i = tid; i < NBK; i += 256)
        cur[i] = bktbase[i] + blockbase[blk * NBK + i];
    __syncthreads();
    int e0 = blk * EPB;
    for (int i = tid; i < EPB; i += 256) {
        int d = dst[e0 + i];
        unsigned s = (unsigned)src[e0 + i];
        unsigned b = (unsigned)d >> 8;
        unsigned pos = atomicAdd(&cur[b], 1u);     // LDS atomic
        ebuf[pos] = ((unsigned)(d & 255) << 20) | s;   // pack d_local | src
    }
}

// ---------- P4: per-bucket CSR finalize (in-place), rowptr + dinv ----------
__global__ __launch_bounds__(256) void k_p4(unsigned* __restrict__ ebuf,
                                            const unsigned* __restrict__ bktbase,
                                            unsigned* __restrict__ rowptr,
                                            float* __restrict__ dinv) {
    __shared__ unsigned eL[MAXBE];
    __shared__ unsigned hist[256];
    __shared__ unsigned sc[256];
    int b = blockIdx.x, tid = threadIdx.x;
    unsigned base = bktbase[b], nE = bktbase[b + 1] - base;
    int n0 = b << 8;
    int nodes = min(256, NN - n0);
    for (unsigned i = tid; i < nE; i += 256) eL[i] = ebuf[base + i];
    hist[tid] = 0;
    __syncthreads();
    for (unsigned i = tid; i < nE; i += 256) atomicAdd(&hist[eL[i] >> 20], 1u);
    __syncthreads();
    unsigned c = hist[tid];
    sc[tid] = c;
    __syncthreads();
    for (int off = 1; off < 256; off <<= 1) {
        unsigned t = (tid >= off) ? sc[tid - off] : 0u;
        __syncthreads();
        sc[tid] += t;
        __syncthreads();
    }
    unsigned excl = sc[tid] - c;
    if (tid < nodes) {
        rowptr[n0 + tid] = base + excl;
        dinv[n0 + tid] = rsqrtf((float)c + 1.0f);
    }
    hist[tid] = base + excl;                       // reuse as cursor
    __syncthreads();
    for (unsigned i = tid; i < nE; i += 256) {
        unsigned v = eL[i];
        unsigned pos = atomicAdd(&hist[v >> 20], 1u);
        ebuf[pos] = v & 0xFFFFFu;                  // keep src only
    }
}

// ---------- hw1c[c][n][8] = chunk of (X @ W1) * dinv[n] ----------
__global__ __launch_bounds__(256) void k_mm128(const float* __restrict__ X,
                                               const float* __restrict__ W,
                                               const float* __restrict__ dinv,
                                               float* __restrict__ hw1c) {
    __shared__ float Wls[SD * HD];       // 16 KB
    __shared__ float xT[32][260];        // 33.3 KB
    int tid = threadIdx.x;
    {
        const float4* W4 = (const float4*)W;
        float4* Wl4 = (float4*)Wls;
        for (int i = tid; i < SD * HD / 4; i += 256) Wl4[i] = W4[i];
    }
    int nb = blockIdx.x * 256;
    int g = tid & 7;
    int q = tid >> 3;
    float acc[8][4] = {};
    for (int kc = 0; kc < SD; kc += 32) {
        __syncthreads();
        for (int i = tid; i < 256 * 8; i += 256) {
            int n = i >> 3, k4 = i & 7;
            int node = nb + n;
            float4 v = (node < NN) ? *(const float4*)&X[(size_t)node * SD + kc + k4 * 4]
                                   : make_float4(0.f, 0.f, 0.f, 0.f);
            xT[k4 * 4 + 0][n] = v.x;
            xT[k4 * 4 + 1][n] = v.y;
            xT[k4 * 4 + 2][n] = v.z;
            xT[k4 * 4 + 3][n] = v.w;
        }
        __syncthreads();
#pragma unroll
        for (int kk = 0; kk < 32; ++kk) {
            const float4 xa = *(const float4*)&xT[kk][q * 8];
            const float4 xb = *(const float4*)&xT[kk][q * 8 + 4];
            const float4 wv = *(const float4*)&Wls[(kc + kk) * HD + g * 4];
            acc[0][0] = fmaf(xa.x, wv.x, acc[0][0]);
            acc[0][1] = fmaf(xa.x, wv.y, acc[0][1]);
            acc[0][2] = fmaf(xa.x, wv.z, acc[0][2]);
            acc[0][3] = fmaf(xa.x, wv.w, acc[0][3]);
            acc[1][0] = fmaf(xa.y, wv.x, acc[1][0]);
            acc[1][1] = fmaf(xa.y, wv.y, acc[1][1]);
            acc[1][2] = fmaf(xa.y, wv.z, acc[1][2]);
            acc[1][3] = fmaf(xa.y, wv.w, acc[1][3]);
            acc[2][0] = fmaf(xa.z, wv.x, acc[2][0]);
            acc[2][1] = fmaf(xa.z, wv.y, acc[2][1]);
            acc[2][2] = fmaf(xa.z, wv.z, acc[2][2]);
            acc[2][3] = fmaf(xa.z, wv.w, acc[2][3]);
            acc[3][0] = fmaf(xa.w, wv.x, acc[3][0]);
            acc[3][1] = fmaf(xa.w, wv.y, acc[3][1]);
            acc[3][2] = fmaf(xa.w, wv.z, acc[3][2]);
            acc[3][3] = fmaf(xa.w, wv.w, acc[3][3]);
            acc[4][0] = fmaf(xb.x, wv.x, acc[4][0]);
            acc[4][1] = fmaf(xb.x, wv.y, acc[4][1]);
            acc[4][2] = fmaf(xb.x, wv.z, acc[4][2]);
            acc[4][3] = fmaf(xb.x, wv.w, acc[4][3]);
            acc[5][0] = fmaf(xb.y, wv.x, acc[5][0]);
            acc[5][1] = fmaf(xb.y, wv.y, acc[5][1]);
            acc[5][2] = fmaf(xb.y, wv.z, acc[5][2]);
            acc[5][3] = fmaf(xb.y, wv.w, acc[5][3]);
            acc[6][0] = fmaf(xb.z, wv.x, acc[6][0]);
            acc[6][1] = fmaf(xb.z, wv.y, acc[6][1]);
            acc[6][2] = fmaf(xb.z, wv.z, acc[6][2]);
            acc[6][3] = fmaf(xb.z, wv.w, acc[6][3]);
            acc[7][0] = fmaf(xb.w, wv.x, acc[7][0]);
            acc[7][1] = fmaf(xb.w, wv.y, acc[7][1]);
            acc[7][2] = fmaf(xb.w, wv.z, acc[7][2]);
            acc[7][3] = fmaf(xb.w, wv.w, acc[7][3]);
        }
    }
    int c = g >> 1, jo = (g & 1) * 4;    // chunk, offset within chunk
#pragma unroll
    for (int r = 0; r < 8; ++r) {
        int node = nb + q * 8 + r;
        if (node < NN) {
            float dv = dinv[node];
            float4 o = {acc[r][0] * dv, acc[r][1] * dv, acc[r][2] * dv, acc[r][3] * dv};
            *(float4*)&hw1c[(size_t)c * NN * CW + (size_t)node * CW + jo] = o;
        }
    }
}

// ---------- conv1 aggregation, chunked: vbuf[c][n][8] = dv*(agg+self)+b1 ----------
// 1 node per wave64: 8 edges x 8 features per iteration. slice 3.2MB -> L2-resident.
__global__ __launch_bounds__(256) void k_g1(const unsigned* __restrict__ edat,
                                            const unsigned* __restrict__ rowptr,
                                            const float* __restrict__ dinv,
                                            const float* __restrict__ hwc,
                                            const float* __restrict__ bias,
                                            float* __restrict__ vbuf) {
    int c = blockIdx.y;
    const float* slice = hwc + (size_t)c * NN * CW;
    int tid = threadIdx.x;
    int n = blockIdx.x * 4 + (tid >> 6);           // grid.x = NN/4 exact
    int lane = tid & 63;
    int er = lane >> 3, j = lane & 7;
    unsigned s0 = rowptr[n], s1 = rowptr[n + 1];
    float acc = 0.f;
    unsigned i = s0;
    for (; i + 16 <= s1; i += 16) {                // 2 rows in flight
        unsigned ea = __builtin_nontemporal_load(&edat[i + er]);
        unsigned eb = __builtin_nontemporal_load(&edat[i + 8 + er]);
        float va = slice[(size_t)ea * CW + j];
        float vb = slice[(size_t)eb * CW + j];
        acc += va + vb;
    }
    if (i + 8 <= s1) {
        acc += slice[(size_t)__builtin_nontemporal_load(&edat[i + er]) * CW + j];
        i += 8;
    }
    if (i + er < s1)
        acc += slice[(size_t)__builtin_nontemporal_load(&edat[i + er]) * CW + j];
    acc += __shfl_xor(acc, 8);
    acc += __shfl_xor(acc, 16);
    acc += __shfl_xor(acc, 32);
    float dv = dinv[n];
    float v = dv * (acc + slice[(size_t)n * CW + j]) + bias[c * CW + j];
    if (lane < CW)
        __builtin_nontemporal_store(v, &vbuf[(size_t)c * NN * CW + (size_t)n * CW + j]);
}

// ---------- conv2 transform: h2c[c][n][8] = chunk of (v @ Wh) * dinv ----------
__global__ __launch_bounds__(256) void k_mmB(const float* __restrict__ vbuf,
                                             const float* __restrict__ Wh,
                                             const float* __restrict__ dinv,
                                             float* __restrict__ h2c) {
    __shared__ float Wls[HD * HD];
    int tid = threadIdx.x;
    for (int i = tid; i < HD * HD; i += 256) Wls[i] = Wh[i];
    __syncthreads();
    int n = blockIdx.x * 8 + (tid >> 5);           // grid = NN/8 exact
    int j = tid & 31;
    float vj = vbuf[(size_t)(j >> 3) * NN * CW + (size_t)n * CW + (j & 7)];
    float h2 = 0.f;
#pragma unroll
    for (int jj = 0; jj < 32; ++jj)
        h2 = fmaf(__shfl(vj, jj, 32), Wls[jj * HD + j], h2);
    h2c[(size_t)(j >> 3) * NN * CW + (size_t)n * CW + (j & 7)] = h2 * dinv[n];
}

// ---------- conv2 aggregation + partial head dots per chunk ----------
__global__ __launch_bounds__(256) void k_g2(const unsigned* __restrict__ edat,
                                            const unsigned* __restrict__ rowptr,
                                            const float* __restrict__ dinv,
                                            const float* __restrict__ h2c,
                                            const float* __restrict__ bh,
                                            const float* __restrict__ W2,
                                            const float* __restrict__ Ws,
                                            float2* __restrict__ hpart) {
    int c = blockIdx.y;
    const float* slice = h2c + (size_t)c * NN * CW;
    int tid = threadIdx.x;
    int n = blockIdx.x * 4 + (tid >> 6);
    int lane = tid & 63;
    int er = lane >> 3, j = lane & 7;
    unsigned s0 = rowptr[n], s1 = rowptr[n + 1];
    float acc = 0.f;
    unsigned i = s0;
    for (; i + 16 <= s1; i += 16) {
        unsigned ea = __builtin_nontemporal_load(&edat[i + er]);
        unsigned eb = __builtin_nontemporal_load(&edat[i + 8 + er]);
        float va = slice[(size_t)ea * CW + j];
        float vb = slice[(size_t)eb * CW + j];
        acc += va + vb;
    }
    if (i + 8 <= s1) {
        acc += slice[(size_t)__builtin_nontemporal_load(&edat[i + er]) * CW + j];
        i += 8;
    }
    if (i + er < s1)
        acc += slice[(size_t)__builtin_nontemporal_load(&edat[i + er]) * CW + j];
    acc += __shfl_xor(acc, 8);
    acc += __shfl_xor(acc, 16);
    acc += __shfl_xor(acc, 32);
    float dv = dinv[n];
    float v2 = dv * (acc + slice[(size_t)n * CW + j]) + bh[c * CW + j];
    float pa = fmaxf(v2, 0.f) * W2[c * CW + j];
    float pb = v2 * Ws[c * CW + j];
    pa += __shfl_xor(pa, 1); pb += __shfl_xor(pb, 1);
    pa += __shfl_xor(pa, 2); pb += __shfl_xor(pb, 2);
    pa += __shfl_xor(pa, 4); pb += __shfl_xor(pb, 4);
    if (lane == 0) hpart[(size_t)c * NN + n] = make_float2(pa, pb);
}

// ---------- sum head partials over chunks, scale by dinv ----------
__global__ __launch_bounds__(256) void k_hsum(const float2* __restrict__ hpart,
                                              const float* __restrict__ dinv,
                                              float2* __restrict__ headw) {
    int n = blockIdx.x * 256 + threadIdx.x;
    if (n < NN) {
        float2 s0 = hpart[n];
        float2 s1 = hpart[NN + n];
        float2 s2 = hpart[2 * NN + n];
        float2 s3 = hpart[3 * NN + n];
        float dv = dinv[n];
        headw[n] = make_float2(dv * ((s0.x + s1.x) + (s2.x + s3.x)),
                               dv * ((s0.y + s1.y) + (s2.y + s3.y)));
    }
}

// ---------- head aggregation -> outputs ----------
__global__ __launch_bounds__(256) void k_gscal(const unsigned* __restrict__ edat,
                                               const unsigned* __restrict__ rowptr,
                                               const float* __restrict__ dinv,
                                               const float2* __restrict__ head_w,
                                               const float* __restrict__ b2,
                                               const float* __restrict__ bs,
                                               float* __restrict__ out) {
    int gid = blockIdx.x * 256 + threadIdx.x;        // exact NN*32/256
    int n = gid >> 5, l = gid & 31;
    unsigned s0 = rowptr[n], s1 = rowptr[n + 1];
    float a = 0.f, b = 0.f;
    for (unsigned i = s0 + l; i < s1; i += 32) {
        float2 w = head_w[edat[i]];                  // 8B random, L2-resident table
        a += w.x; b += w.y;
    }
#pragma unroll
    for (int off = 16; off > 0; off >>= 1) {
        a += __shfl_xor(a, off, 32);
        b += __shfl_xor(b, off, 32);
    }
    if (l == 0) {
        float dv = dinv[n];
        float2 self = head_w[n];
        out[n]      = dv * (a + self.x) + b2[0];
        out[NN + n] = dv * (b + self.y) + bs[0];
    }
}

extern "C" void kernel_launch(void* const* d_in, const int* in_sizes, int n_in,
                              void* d_out, int out_size, void* d_ws, size_t ws_size,
                              hipStream_t stream) {
    const float* x   = (const float*)d_in[0];
    const int*   ei  = (const int*)d_in[1];
    const int*   src = ei;
    const int*   dst = ei + NE;
    const float* W1  = (const float*)d_in[2];
    const float* b1  = (const float*)d_in[3];
    const float* Wh  = (const float*)d_in[4];
    const float* bh  = (const float*)d_in[5];
    const float* W2  = (const float*)d_in[6];
    const float* b2  = (const float*)d_in[7];
    const float* Wsp = (const float*)d_in[8];
    const float* bs  = (const float*)d_in[9];
    float* out = (float*)d_out;

    // workspace (u32 words), ~33.6 MB:
    // edat 0..1.6M | hw1c(=h2c) 1.6M..4.8M | vbuf 4.8M..8.0M
    //   (blockbase aliases vbuf start, dead before g1; hpart aliases vbuf, live after mmB)
    // rowptr @8.0M | bktcnt @8.100004M | bktbase @8.1004M | dinv @8.1008M | headw @8.2008M
    unsigned* w         = (unsigned*)d_ws;
    unsigned* edat      = w;
    float*    hw1c      = (float*)(w + 1600000);      // also h2c (hw1c dead after g1)
    float*    vbuf      = (float*)(w + 4800000);
    unsigned* blockbase = w + 4800000;                // dead after p3
    float2*   hpart     = (float2*)(w + 4800000);     // live after mmB (vbuf dead)
    unsigned* rowptr    = w + 8000000;
    unsigned* bktcnt    = w + 8100004;
    unsigned* bktbase   = w + 8100400;
    float*    dinv      = (float*)(w + 8100800);
    float2*   headw     = (float2*)(w + 8200800);

    // CSR build: bucketed counting sort, no global data atomics
    hipMemsetAsync(bktcnt, 0, NBK * sizeof(unsigned), stream);
    k_p1<<<NBLK, 256, 0, stream>>>(dst, bktcnt, blockbase);
    k_p2<<<1, 512, 0, stream>>>(bktcnt, bktbase, rowptr);
    k_p3<<<NBLK, 256, 0, stream>>>(src, dst, bktbase, blockbase, edat);
    k_p4<<<NBK, 256, 0, stream>>>(edat, bktbase, rowptr, dinv);

    // conv1 transform, chunk-major output
    k_mm128<<<(NN + 255) / 256, 256, 0, stream>>>(x, W1, dinv, hw1c);
    // conv1 aggregate: 4 L2-resident chunk passes (y = chunk)
    k_g1<<<dim3(NN / 4, NCH), 256, 0, stream>>>(edat, rowptr, dinv, hw1c, b1, vbuf);
    // conv2 transform (un-fused so chunks stay independent)
    k_mmB<<<NN / 8, 256, 0, stream>>>(vbuf, Wh, dinv, hw1c);   // hw1c reused as h2c
    // conv2 aggregate + partial heads per chunk
    k_g2<<<dim3(NN / 4, NCH), 256, 0, stream>>>(edat, rowptr, dinv, hw1c, bh, W2, Wsp, hpart);
    // combine head partials
    k_hsum<<<(NN + 255) / 256, 256, 0, stream>>>(hpart, dinv, headw);
    // head aggregation -> outputs
    k_gscal<<<NN * HD / 256, 256, 0, stream>>>(edat, rowptr, dinv, headw, b2, bs, out);
}

// Round 13
// 302.739 us; speedup vs baseline: 1.6605x; 1.6605x over previous
//
#include <hip/hip_runtime.h>

#define NN 100000
#define NE 1600000
#define SD 128
#define HD 32
#define RW 16          // bf16 row width in u32 words (32 features x 2B = 64B)
#define NBK 391        // buckets of 256 nodes
#define EPB 4000       // edges per block in P1/P3
#define NBLK 400       // NBLK*EPB == NE
#define MAXBE 6144     // max edges per bucket

static __device__ __forceinline__ unsigned bf16pk(float a, float b) {
    unsigned ua = __float_as_uint(a);
    ua = (ua + 0x7fffu + ((ua >> 16) & 1u)) >> 16;       // RNE
    unsigned ub = __float_as_uint(b);
    ub = (ub + 0x7fffu + ((ub >> 16) & 1u)) >> 16;
    return ua | (ub << 16);
}
static __device__ __forceinline__ float bflo(unsigned u) { return __uint_as_float(u << 16); }
static __device__ __forceinline__ float bfhi(unsigned u) { return __uint_as_float(u & 0xffff0000u); }

// ---------- P1: per-block bucket histogram + global reservation ----------
__global__ __launch_bounds__(256) void k_p1(const int* __restrict__ dst,
                                            unsigned* __restrict__ bktcnt,
                                            unsigned* __restrict__ blockbase) {
    __shared__ unsigned h[NBK];
    int blk = blockIdx.x, tid = threadIdx.x;
    for (int i = tid; i < NBK; i += 256) h[i] = 0;
    __syncthreads();
    int e0 = blk * EPB;
    for (int i = tid; i < EPB; i += 256)
        atomicAdd(&h[(unsigned)dst[e0 + i] >> 8], 1u);
    __syncthreads();
    for (int i = tid; i < NBK; i += 256)
        blockbase[blk * NBK + i] = atomicAdd(&bktcnt[i], h[i]);
}

// ---------- P2: scan bucket totals -> bucket bases ----------
__global__ __launch_bounds__(512) void k_p2(const unsigned* __restrict__ bktcnt,
                                            unsigned* __restrict__ bktbase,
                                            unsigned* __restrict__ rowptr) {
    __shared__ unsigned sc[512];
    int tid = threadIdx.x;
    unsigned c = (tid < NBK) ? bktcnt[tid] : 0u;
    sc[tid] = c;
    __syncthreads();
    for (int off = 1; off < 512; off <<= 1) {
        unsigned t = (tid >= off) ? sc[tid - off] : 0u;
        __syncthreads();
        sc[tid] += t;
        __syncthreads();
    }
    if (tid <= NBK) bktbase[tid] = sc[tid] - c;
    if (tid == 0) rowptr[NN] = NE;
}

// ---------- P3: scatter edges into buckets ----------
__global__ __launch_bounds__(256) void k_p3(const int* __restrict__ src,
                                            const int* __restrict__ dst,
                                            const unsigned* __restrict__ bktbase,
                                            const unsigned* __restrict__ blockbase,
                                            unsigned* __restrict__ ebuf) {
    __shared__ unsigned cur[NBK];
    int blk = blockIdx.x, tid = threadIdx.x;
    for (int i = tid; i < NBK; i += 256)
        cur[i] = bktbase[i] + blockbase[blk * NBK + i];
    __syncthreads();
    int e0 = blk * EPB;
    for (int i = tid; i < EPB; i += 256) {
        int d = dst[e0 + i];
        unsigned s = (unsigned)src[e0 + i];
        unsigned b = (unsigned)d >> 8;
        unsigned pos = atomicAdd(&cur[b], 1u);
        ebuf[pos] = ((unsigned)(d & 255) << 20) | s;
    }
}

// ---------- P4: per-bucket CSR finalize (in-place), rowptr + dinv ----------
__global__ __launch_bounds__(256) void k_p4(unsigned* __restrict__ ebuf,
                                            const unsigned* __restrict__ bktbase,
                                            unsigned* __restrict__ rowptr,
                                            float* __restrict__ dinv) {
    __shared__ unsigned eL[MAXBE];
    __shared__ unsigned hist[256];
    __shared__ unsigned sc[256];
    int b = blockIdx.x, tid = threadIdx.x;
    unsigned base = bktbase[b], nE = bktbase[b + 1] - base;
    int n0 = b << 8;
    int nodes = min(256, NN - n0);
    for (unsigned i = tid; i < nE; i += 256) eL[i] = ebuf[base + i];
    hist[tid] = 0;
    __syncthreads();
    for (unsigned i = tid; i < nE; i += 256) atomicAdd(&hist[eL[i] >> 20], 1u);
    __syncthreads();
    unsigned c = hist[tid];
    sc[tid] = c;
    __syncthreads();
    for (int off = 1; off < 256; off <<= 1) {
        unsigned t = (tid >= off) ? sc[tid - off] : 0u;
        __syncthreads();
        sc[tid] += t;
        __syncthreads();
    }
    unsigned excl = sc[tid] - c;
    if (tid < nodes) {
        rowptr[n0 + tid] = base + excl;
        dinv[n0 + tid] = rsqrtf((float)c + 1.0f);
    }
    hist[tid] = base + excl;
    __syncthreads();
    for (unsigned i = tid; i < nE; i += 256) {
        unsigned v = eL[i];
        unsigned pos = atomicAdd(&hist[v >> 20], 1u);
        ebuf[pos] = v & 0xFFFFFu;
    }
}

// ---------- hw1 (bf16) = (X @ W1) * dinv[n] : 256 nodes/block, thread = 8n x 4f ----------
__global__ __launch_bounds__(256) void k_mm128(const float* __restrict__ X,
                                               const float* __restrict__ W,
                                               const float* __restrict__ dinv,
                                               unsigned* __restrict__ hw1) {
    __shared__ float Wls[SD * HD];
    __shared__ float xT[32][260];
    int tid = threadIdx.x;
    {
        const float4* W4 = (const float4*)W;
        float4* Wl4 = (float4*)Wls;
        for (int i = tid; i < SD * HD / 4; i += 256) Wl4[i] = W4[i];
    }
    int nb = blockIdx.x * 256;
    int g = tid & 7;
    int q = tid >> 3;
    float acc[8][4] = {};
    for (int kc = 0; kc < SD; kc += 32) {
        __syncthreads();
        for (int i = tid; i < 256 * 8; i += 256) {
            int n = i >> 3, k4 = i & 7;
            int node = nb + n;
            float4 v = (node < NN) ? *(const float4*)&X[(size_t)node * SD + kc + k4 * 4]
                                   : make_float4(0.f, 0.f, 0.f, 0.f);
            xT[k4 * 4 + 0][n] = v.x;
            xT[k4 * 4 + 1][n] = v.y;
            xT[k4 * 4 + 2][n] = v.z;
            xT[k4 * 4 + 3][n] = v.w;
        }
        __syncthreads();
#pragma unroll
        for (int kk = 0; kk < 32; ++kk) {
            const float4 xa = *(const float4*)&xT[kk][q * 8];
            const float4 xb = *(const float4*)&xT[kk][q * 8 + 4];
            const float4 wv = *(const float4*)&Wls[(kc + kk) * HD + g * 4];
            acc[0][0] = fmaf(xa.x, wv.x, acc[0][0]);
            acc[0][1] = fmaf(xa.x, wv.y, acc[0][1]);
            acc[0][2] = fmaf(xa.x, wv.z, acc[0][2]);
            acc[0][3] = fmaf(xa.x, wv.w, acc[0][3]);
            acc[1][0] = fmaf(xa.y, wv.x, acc[1][0]);
            acc[1][1] = fmaf(xa.y, wv.y, acc[1][1]);
            acc[1][2] = fmaf(xa.y, wv.z, acc[1][2]);
            acc[1][3] = fmaf(xa.y, wv.w, acc[1][3]);
            acc[2][0] = fmaf(xa.z, wv.x, acc[2][0]);
            acc[2][1] = fmaf(xa.z, wv.y, acc[2][1]);
            acc[2][2] = fmaf(xa.z, wv.z, acc[2][2]);
            acc[2][3] = fmaf(xa.z, wv.w, acc[2][3]);
            acc[3][0] = fmaf(xa.w, wv.x, acc[3][0]);
            acc[3][1] = fmaf(xa.w, wv.y, acc[3][1]);
            acc[3][2] = fmaf(xa.w, wv.z, acc[3][2]);
            acc[3][3] = fmaf(xa.w, wv.w, acc[3][3]);
            acc[4][0] = fmaf(xb.x, wv.x, acc[4][0]);
            acc[4][1] = fmaf(xb.x, wv.y, acc[4][1]);
            acc[4][2] = fmaf(xb.x, wv.z, acc[4][2]);
            acc[4][3] = fmaf(xb.x, wv.w, acc[4][3]);
            acc[5][0] = fmaf(xb.y, wv.x, acc[5][0]);
            acc[5][1] = fmaf(xb.y, wv.y, acc[5][1]);
            acc[5][2] = fmaf(xb.y, wv.z, acc[5][2]);
            acc[5][3] = fmaf(xb.y, wv.w, acc[5][3]);
            acc[6][0] = fmaf(xb.z, wv.x, acc[6][0]);
            acc[6][1] = fmaf(xb.z, wv.y, acc[6][1]);
            acc[6][2] = fmaf(xb.z, wv.z, acc[6][2]);
            acc[6][3] = fmaf(xb.z, wv.w, acc[6][3]);
            acc[7][0] = fmaf(xb.w, wv.x, acc[7][0]);
            acc[7][1] = fmaf(xb.w, wv.y, acc[7][1]);
            acc[7][2] = fmaf(xb.w, wv.z, acc[7][2]);
            acc[7][3] = fmaf(xb.w, wv.w, acc[7][3]);
        }
    }
#pragma unroll
    for (int r = 0; r < 8; ++r) {
        int node = nb + q * 8 + r;
        if (node < NN) {
            float dv = dinv[node];
            uint2 pk = make_uint2(bf16pk(acc[r][0] * dv, acc[r][1] * dv),
                                  bf16pk(acc[r][2] * dv, acc[r][3] * dv));
            *(uint2*)&hw1[(size_t)node * RW + g * 2] = pk;
        }
    }
}

// ---------- gather over bf16 table; 32 lanes/node: e=lane>>4 (2 edges), p=lane&15 ----------
// v[2p..2p+1] = dinv[n]*(sum_in tbl[s] + tbl[n]) + bias
// MODE 1: hw2[n] (bf16) = (v @ Wa) * dinv[n]     (fused 32x32 matmul via width-16 shfl)
// MODE 2: headw[n] = { dinv*sum relu(v)*Wa, dinv*sum v*Wb }
template <int MODE>
__global__ __launch_bounds__(256) void k_gather(const unsigned* __restrict__ edat,
                                                const unsigned* __restrict__ rowptr,
                                                const float* __restrict__ dinv,
                                                const unsigned* __restrict__ tbl,
                                                const float* __restrict__ bias,
                                                const float* __restrict__ Wa,
                                                const float* __restrict__ Wb,
                                                unsigned* __restrict__ outt,
                                                float2* __restrict__ headw) {
    __shared__ float Wls[HD * HD];
    int tid = threadIdx.x;
    if (MODE == 1) {
        for (int i = tid; i < HD * HD; i += 256) Wls[i] = Wa[i];
        __syncthreads();
    }
    int n = blockIdx.x * 8 + (tid >> 5);             // grid = NN/8 exact
    int l = tid & 31;
    int e = l >> 4, p = l & 15;
    unsigned s0 = rowptr[n], s1 = rowptr[n + 1];
    float acc0 = 0.f, acc1 = 0.f;
    unsigned i = s0;
    for (; i + 4 <= s1; i += 4) {                    // 4 edges in flight
        unsigned ea = edat[i + e], eb = edat[i + 2 + e];
        unsigned ua = tbl[(size_t)ea * RW + p];      // 64B row: 16 lanes x 4B coalesced
        unsigned ub = tbl[(size_t)eb * RW + p];
        acc0 += bflo(ua) + bflo(ub);
        acc1 += bfhi(ua) + bfhi(ub);
    }
    if (i + 2 <= s1) {
        unsigned ua = tbl[(size_t)edat[i + e] * RW + p];
        acc0 += bflo(ua); acc1 += bfhi(ua);
        i += 2;
    }
    if (i + e < s1) {
        unsigned ua = tbl[(size_t)edat[i + e] * RW + p];
        acc0 += bflo(ua); acc1 += bfhi(ua);
    }
    acc0 += __shfl_xor(acc0, 16);                    // reduce over edge slots
    acc1 += __shfl_xor(acc1, 16);
    float dv = dinv[n];
    unsigned su = tbl[(size_t)n * RW + p];
    float v0 = dv * (acc0 + bflo(su)) + bias[2 * p];
    float v1 = dv * (acc1 + bfhi(su)) + bias[2 * p + 1];
    if (MODE == 1) {
        float o0 = 0.f, o1 = 0.f;
#pragma unroll
        for (int q = 0; q < 16; ++q) {
            float sv0 = __shfl(v0, q, 16);
            float sv1 = __shfl(v1, q, 16);
            o0 += sv0 * Wls[(2 * q) * HD + 2 * p] + sv1 * Wls[(2 * q + 1) * HD + 2 * p];
            o1 += sv0 * Wls[(2 * q) * HD + 2 * p + 1] + sv1 * Wls[(2 * q + 1) * HD + 2 * p + 1];
        }
        if (l < 16) outt[(size_t)n * RW + p] = bf16pk(o0 * dv, o1 * dv);
    } else {
        float pa = fmaxf(v0, 0.f) * Wa[2 * p] + fmaxf(v1, 0.f) * Wa[2 * p + 1];
        float pb = v0 * Wb[2 * p] + v1 * Wb[2 * p + 1];
#pragma unroll
        for (int off = 8; off > 0; off >>= 1) {
            pa += __shfl_xor(pa, off);
            pb += __shfl_xor(pb, off);
        }
        if (l == 0) headw[n] = make_float2(pa * dv, pb * dv);
    }
}

// ---------- head aggregation -> outputs ----------
__global__ __launch_bounds__(256) void k_gscal(const unsigned* __restrict__ edat,
                                               const unsigned* __restrict__ rowptr,
                                               const float* __restrict__ dinv,
                                               const float2* __restrict__ head_w,
                                               const float* __restrict__ b2,
                                               const float* __restrict__ bs,
                                               float* __restrict__ out) {
    int gid = blockIdx.x * 256 + threadIdx.x;        // exact NN*32/256
    int n = gid >> 5, l = gid & 31;
    unsigned s0 = rowptr[n], s1 = rowptr[n + 1];
    float a = 0.f, b = 0.f;
    for (unsigned i = s0 + l; i < s1; i += 32) {
        float2 w = head_w[edat[i]];
        a += w.x; b += w.y;
    }
#pragma unroll
    for (int off = 16; off > 0; off >>= 1) {
        a += __shfl_xor(a, off, 32);
        b += __shfl_xor(b, off, 32);
    }
    if (l == 0) {
        float dv = dinv[n];
        float2 self = head_w[n];
        out[n]      = dv * (a + self.x) + b2[0];
        out[NN + n] = dv * (b + self.y) + bs[0];
    }
}

extern "C" void kernel_launch(void* const* d_in, const int* in_sizes, int n_in,
                              void* d_out, int out_size, void* d_ws, size_t ws_size,
                              hipStream_t stream) {
    const float* x   = (const float*)d_in[0];
    const int*   ei  = (const int*)d_in[1];
    const int*   src = ei;
    const int*   dst = ei + NE;
    const float* W1  = (const float*)d_in[2];
    const float* b1  = (const float*)d_in[3];
    const float* Wh  = (const float*)d_in[4];
    const float* bh  = (const float*)d_in[5];
    const float* W2  = (const float*)d_in[6];
    const float* b2  = (const float*)d_in[7];
    const float* Wsp = (const float*)d_in[8];
    const float* bs  = (const float*)d_in[9];
    float* out = (float*)d_out;

    // workspace (u32 words), ~22 MB:
    // edat 0..1.6M | hw1 1.6M..3.2M (bf16) | hw2 3.2M..4.8M (bf16) |
    // blockbase 4.8M..4.9564M | rowptr @5.0M | bktcnt @5.1M | bktbase @5.1005M |
    // dinv @5.101M | headw @5.201M (float2[NN])
    unsigned* w         = (unsigned*)d_ws;
    unsigned* edat      = w;
    unsigned* hw1       = w + 1600000;
    unsigned* hw2       = w + 3200000;
    unsigned* blockbase = w + 4800000;
    unsigned* rowptr    = w + 5000000;
    unsigned* bktcnt    = w + 5100004;
    unsigned* bktbase   = w + 5100500;
    float*    dinv      = (float*)(w + 5101000);
    float2*   headw     = (float2*)(w + 5201000);

    // CSR build: bucketed counting sort, no global data atomics
    hipMemsetAsync(bktcnt, 0, NBK * sizeof(unsigned), stream);
    k_p1<<<NBLK, 256, 0, stream>>>(dst, bktcnt, blockbase);
    k_p2<<<1, 512, 0, stream>>>(bktcnt, bktbase, rowptr);
    k_p3<<<NBLK, 256, 0, stream>>>(src, dst, bktbase, blockbase, edat);
    k_p4<<<NBK, 256, 0, stream>>>(edat, bktbase, rowptr, dinv);

    // conv1 transform -> bf16 table (pre-scaled by dinv)
    k_mm128<<<(NN + 255) / 256, 256, 0, stream>>>(x, W1, dinv, hw1);
    // conv1 aggregate + fused conv2 transform -> bf16 table
    k_gather<1><<<NN / 8, 256, 0, stream>>>(edat, rowptr, dinv, hw1, b1, Wh, nullptr, hw2, nullptr);
    // conv2 aggregate + fused heads -> headw (f32)
    k_gather<2><<<NN / 8, 256, 0, stream>>>(edat, rowptr, dinv, hw2, bh, W2, Wsp, nullptr, headw);
    // head aggregation -> outputs
    k_gscal<<<NN * HD / 256, 256, 0, stream>>>(edat, rowptr, dinv, headw, b2, bs, out);
}

// Round 14
// 296.698 us; speedup vs baseline: 1.6943x; 1.0204x over previous
//
#include <hip/hip_runtime.h>

#define NN 100000
#define NE 1600000
#define SD 128
#define HD 32
#define RW 16          // bf16 row width in u32 words (32 features x 2B = 64B)
#define NBK 391        // buckets of 256 nodes
#define EPB 4000       // edges per block in P1/P3
#define NBLK 400       // NBLK*EPB == NE
#define MAXBE 6144     // max edges per bucket

static __device__ __forceinline__ unsigned bf16pk(float a, float b) {
    unsigned ua = __float_as_uint(a);
    ua = (ua + 0x7fffu + ((ua >> 16) & 1u)) >> 16;       // RNE
    unsigned ub = __float_as_uint(b);
    ub = (ub + 0x7fffu + ((ub >> 16) & 1u)) >> 16;
    return ua | (ub << 16);
}
static __device__ __forceinline__ unsigned short bf16r(float a) {
    unsigned ua = __float_as_uint(a);
    return (unsigned short)((ua + 0x7fffu + ((ua >> 16) & 1u)) >> 16);
}
static __device__ __forceinline__ float bfup(unsigned short u) {
    return __uint_as_float((unsigned)u << 16);
}

// ---------- P1: per-block bucket histogram + global reservation ----------
__global__ __launch_bounds__(256) void k_p1(const int* __restrict__ dst,
                                            unsigned* __restrict__ bktcnt,
                                            unsigned* __restrict__ blockbase) {
    __shared__ unsigned h[NBK];
    int blk = blockIdx.x, tid = threadIdx.x;
    for (int i = tid; i < NBK; i += 256) h[i] = 0;
    __syncthreads();
    int e0 = blk * EPB;
    for (int i = tid; i < EPB; i += 256)
        atomicAdd(&h[(unsigned)dst[e0 + i] >> 8], 1u);
    __syncthreads();
    for (int i = tid; i < NBK; i += 256)
        blockbase[blk * NBK + i] = atomicAdd(&bktcnt[i], h[i]);
}

// ---------- P2: scan bucket totals -> bucket bases ----------
__global__ __launch_bounds__(512) void k_p2(const unsigned* __restrict__ bktcnt,
                                            unsigned* __restrict__ bktbase,
                                            unsigned* __restrict__ rowptr) {
    __shared__ unsigned sc[512];
    int tid = threadIdx.x;
    unsigned c = (tid < NBK) ? bktcnt[tid] : 0u;
    sc[tid] = c;
    __syncthreads();
    for (int off = 1; off < 512; off <<= 1) {
        unsigned t = (tid >= off) ? sc[tid - off] : 0u;
        __syncthreads();
        sc[tid] += t;
        __syncthreads();
    }
    if (tid <= NBK) bktbase[tid] = sc[tid] - c;
    if (tid == 0) rowptr[NN] = NE;
}

// ---------- P3: scatter edges into buckets ----------
__global__ __launch_bounds__(256) void k_p3(const int* __restrict__ src,
                                            const int* __restrict__ dst,
                                            const unsigned* __restrict__ bktbase,
                                            const unsigned* __restrict__ blockbase,
                                            unsigned* __restrict__ ebuf) {
    __shared__ unsigned cur[NBK];
    int blk = blockIdx.x, tid = threadIdx.x;
    for (int i = tid; i < NBK; i += 256)
        cur[i] = bktbase[i] + blockbase[blk * NBK + i];
    __syncthreads();
    int e0 = blk * EPB;
    for (int i = tid; i < EPB; i += 256) {
        int d = dst[e0 + i];
        unsigned s = (unsigned)src[e0 + i];
        unsigned b = (unsigned)d >> 8;
        unsigned pos = atomicAdd(&cur[b], 1u);
        ebuf[pos] = ((unsigned)(d & 255) << 20) | s;
    }
}

// ---------- P4: per-bucket CSR finalize (in-place), rowptr + dinv ----------
__global__ __launch_bounds__(256) void k_p4(unsigned* __restrict__ ebuf,
                                            const unsigned* __restrict__ bktbase,
                                            unsigned* __restrict__ rowptr,
                                            float* __restrict__ dinv) {
    __shared__ unsigned eL[MAXBE];
    __shared__ unsigned hist[256];
    __shared__ unsigned sc[256];
    int b = blockIdx.x, tid = threadIdx.x;
    unsigned base = bktbase[b], nE = bktbase[b + 1] - base;
    int n0 = b << 8;
    int nodes = min(256, NN - n0);
    for (unsigned i = tid; i < nE; i += 256) eL[i] = ebuf[base + i];
    hist[tid] = 0;
    __syncthreads();
    for (unsigned i = tid; i < nE; i += 256) atomicAdd(&hist[eL[i] >> 20], 1u);
    __syncthreads();
    unsigned c = hist[tid];
    sc[tid] = c;
    __syncthreads();
    for (int off = 1; off < 256; off <<= 1) {
        unsigned t = (tid >= off) ? sc[tid - off] : 0u;
        __syncthreads();
        sc[tid] += t;
        __syncthreads();
    }
    unsigned excl = sc[tid] - c;
    if (tid < nodes) {
        rowptr[n0 + tid] = base + excl;
        dinv[n0 + tid] = rsqrtf((float)c + 1.0f);
    }
    hist[tid] = base + excl;
    __syncthreads();
    for (unsigned i = tid; i < nE; i += 256) {
        unsigned v = eL[i];
        unsigned pos = atomicAdd(&hist[v >> 20], 1u);
        ebuf[pos] = v & 0xFFFFFu;
    }
}

// ---------- hw1 (bf16) = (X @ W1) * dinv[n] : 256 nodes/block, thread = 8n x 4f ----------
__global__ __launch_bounds__(256) void k_mm128(const float* __restrict__ X,
                                               const float* __restrict__ W,
                                               const float* __restrict__ dinv,
                                               unsigned* __restrict__ hw1) {
    __shared__ float Wls[SD * HD];
    __shared__ float xT[32][260];
    int tid = threadIdx.x;
    {
        const float4* W4 = (const float4*)W;
        float4* Wl4 = (float4*)Wls;
        for (int i = tid; i < SD * HD / 4; i += 256) Wl4[i] = W4[i];
    }
    int nb = blockIdx.x * 256;
    int g = tid & 7;
    int q = tid >> 3;
    float acc[8][4] = {};
    for (int kc = 0; kc < SD; kc += 32) {
        __syncthreads();
        for (int i = tid; i < 256 * 8; i += 256) {
            int n = i >> 3, k4 = i & 7;
            int node = nb + n;
            float4 v = (node < NN) ? *(const float4*)&X[(size_t)node * SD + kc + k4 * 4]
                                   : make_float4(0.f, 0.f, 0.f, 0.f);
            xT[k4 * 4 + 0][n] = v.x;
            xT[k4 * 4 + 1][n] = v.y;
            xT[k4 * 4 + 2][n] = v.z;
            xT[k4 * 4 + 3][n] = v.w;
        }
        __syncthreads();
#pragma unroll
        for (int kk = 0; kk < 32; ++kk) {
            const float4 xa = *(const float4*)&xT[kk][q * 8];
            const float4 xb = *(const float4*)&xT[kk][q * 8 + 4];
            const float4 wv = *(const float4*)&Wls[(kc + kk) * HD + g * 4];
            acc[0][0] = fmaf(xa.x, wv.x, acc[0][0]);
            acc[0][1] = fmaf(xa.x, wv.y, acc[0][1]);
            acc[0][2] = fmaf(xa.x, wv.z, acc[0][2]);
            acc[0][3] = fmaf(xa.x, wv.w, acc[0][3]);
            acc[1][0] = fmaf(xa.y, wv.x, acc[1][0]);
            acc[1][1] = fmaf(xa.y, wv.y, acc[1][1]);
            acc[1][2] = fmaf(xa.y, wv.z, acc[1][2]);
            acc[1][3] = fmaf(xa.y, wv.w, acc[1][3]);
            acc[2][0] = fmaf(xa.z, wv.x, acc[2][0]);
            acc[2][1] = fmaf(xa.z, wv.y, acc[2][1]);
            acc[2][2] = fmaf(xa.z, wv.z, acc[2][2]);
            acc[2][3] = fmaf(xa.z, wv.w, acc[2][3]);
            acc[3][0] = fmaf(xa.w, wv.x, acc[3][0]);
            acc[3][1] = fmaf(xa.w, wv.y, acc[3][1]);
            acc[3][2] = fmaf(xa.w, wv.z, acc[3][2]);
            acc[3][3] = fmaf(xa.w, wv.w, acc[3][3]);
            acc[4][0] = fmaf(xb.x, wv.x, acc[4][0]);
            acc[4][1] = fmaf(xb.x, wv.y, acc[4][1]);
            acc[4][2] = fmaf(xb.x, wv.z, acc[4][2]);
            acc[4][3] = fmaf(xb.x, wv.w, acc[4][3]);
            acc[5][0] = fmaf(xb.y, wv.x, acc[5][0]);
            acc[5][1] = fmaf(xb.y, wv.y, acc[5][1]);
            acc[5][2] = fmaf(xb.y, wv.z, acc[5][2]);
            acc[5][3] = fmaf(xb.y, wv.w, acc[5][3]);
            acc[6][0] = fmaf(xb.z, wv.x, acc[6][0]);
            acc[6][1] = fmaf(xb.z, wv.y, acc[6][1]);
            acc[6][2] = fmaf(xb.z, wv.z, acc[6][2]);
            acc[6][3] = fmaf(xb.z, wv.w, acc[6][3]);
            acc[7][0] = fmaf(xb.w, wv.x, acc[7][0]);
            acc[7][1] = fmaf(xb.w, wv.y, acc[7][1]);
            acc[7][2] = fmaf(xb.w, wv.z, acc[7][2]);
            acc[7][3] = fmaf(xb.w, wv.w, acc[7][3]);
        }
    }
#pragma unroll
    for (int r = 0; r < 8; ++r) {
        int node = nb + q * 8 + r;
        if (node < NN) {
            float dv = dinv[node];
            uint2 pk = make_uint2(bf16pk(acc[r][0] * dv, acc[r][1] * dv),
                                  bf16pk(acc[r][2] * dv, acc[r][3] * dv));
            *(uint2*)&hw1[(size_t)node * RW + g * 2] = pk;
        }
    }
}

// ---------- gather over bf16 table; 32 lanes = 32 features, ushort loads ----------
// v[j] = dinv[n]*(sum_in tbl[s][j] + tbl[n][j]) + bias[j]
// MODE 1: hw2[n][j] (bf16) = (v @ Wa)[j] * dinv[n]   (32-wide shfl matmul)
// MODE 2: headw[n] = { dinv*sum relu(v)*Wa, dinv*sum v*Wb }
template <int MODE>
__global__ __launch_bounds__(256) void k_gather(const unsigned* __restrict__ edat,
                                                const unsigned* __restrict__ rowptr,
                                                const float* __restrict__ dinv,
                                                const unsigned short* __restrict__ tbl,
                                                const float* __restrict__ bias,
                                                const float* __restrict__ Wa,
                                                const float* __restrict__ Wb,
                                                unsigned short* __restrict__ outt,
                                                float2* __restrict__ headw) {
    __shared__ float Wls[HD * HD];
    int tid = threadIdx.x;
    if (MODE == 1) {
        for (int i = tid; i < HD * HD; i += 256) Wls[i] = Wa[i];
        __syncthreads();
    }
    int gid = blockIdx.x * 256 + tid;                // exact NN*32/256
    int n = gid >> 5, j = gid & 31;
    unsigned s0 = rowptr[n], s1 = rowptr[n + 1];
    float acc = 0.f;
    unsigned i = s0;
    for (; i + 4 <= s1; i += 4) {                    // 4 row-loads in flight per lane
        unsigned e0 = edat[i], e1 = edat[i + 1], e2 = edat[i + 2], e3 = edat[i + 3];
        float v0 = bfup(tbl[(size_t)e0 * HD + j]);   // 64B/row, coalesced across 32 lanes
        float v1 = bfup(tbl[(size_t)e1 * HD + j]);
        float v2 = bfup(tbl[(size_t)e2 * HD + j]);
        float v3 = bfup(tbl[(size_t)e3 * HD + j]);
        acc += (v0 + v1) + (v2 + v3);
    }
    for (; i < s1; ++i) acc += bfup(tbl[(size_t)edat[i] * HD + j]);
    float dv = dinv[n];
    float v = dv * (acc + bfup(tbl[(size_t)n * HD + j])) + bias[j];
    if (MODE == 1) {
        float h2 = 0.f;
#pragma unroll
        for (int jj = 0; jj < 32; ++jj)
            h2 = fmaf(__shfl(v, jj, 32), Wls[jj * HD + j], h2);
        outt[(size_t)n * HD + j] = bf16r(h2 * dv);
    } else {
        float a = fmaxf(v, 0.f) * Wa[j];
        float b = v * Wb[j];
#pragma unroll
        for (int off = 16; off > 0; off >>= 1) {
            a += __shfl_xor(a, off, 32);
            b += __shfl_xor(b, off, 32);
        }
        if (j == 0) headw[n] = make_float2(a * dv, b * dv);
    }
}

// ---------- head aggregation -> outputs ----------
__global__ __launch_bounds__(256) void k_gscal(const unsigned* __restrict__ edat,
                                               const unsigned* __restrict__ rowptr,
                                               const float* __restrict__ dinv,
                                               const float2* __restrict__ head_w,
                                               const float* __restrict__ b2,
                                               const float* __restrict__ bs,
                                               float* __restrict__ out) {
    int gid = blockIdx.x * 256 + threadIdx.x;        // exact NN*32/256
    int n = gid >> 5, l = gid & 31;
    unsigned s0 = rowptr[n], s1 = rowptr[n + 1];
    float a = 0.f, b = 0.f;
    for (unsigned i = s0 + l; i < s1; i += 32) {
        float2 w = head_w[edat[i]];
        a += w.x; b += w.y;
    }
#pragma unroll
    for (int off = 16; off > 0; off >>= 1) {
        a += __shfl_xor(a, off, 32);
        b += __shfl_xor(b, off, 32);
    }
    if (l == 0) {
        float dv = dinv[n];
        float2 self = head_w[n];
        out[n]      = dv * (a + self.x) + b2[0];
        out[NN + n] = dv * (b + self.y) + bs[0];
    }
}

extern "C" void kernel_launch(void* const* d_in, const int* in_sizes, int n_in,
                              void* d_out, int out_size, void* d_ws, size_t ws_size,
                              hipStream_t stream) {
    const float* x   = (const float*)d_in[0];
    const int*   ei  = (const int*)d_in[1];
    const int*   src = ei;
    const int*   dst = ei + NE;
    const float* W1  = (const float*)d_in[2];
    const float* b1  = (const float*)d_in[3];
    const float* Wh  = (const float*)d_in[4];
    const float* bh  = (const float*)d_in[5];
    const float* W2  = (const float*)d_in[6];
    const float* b2  = (const float*)d_in[7];
    const float* Wsp = (const float*)d_in[8];
    const float* bs  = (const float*)d_in[9];
    float* out = (float*)d_out;

    // workspace (u32 words), ~22 MB:
    // edat 0..1.6M | hw1 1.6M..3.2M (bf16) | hw2 3.2M..4.8M (bf16) |
    // blockbase 4.8M..4.9564M | rowptr @5.0M | bktcnt @5.1M | bktbase @5.1005M |
    // dinv @5.101M | headw @5.201M (float2[NN])
    unsigned* w         = (unsigned*)d_ws;
    unsigned* edat      = w;
    unsigned* hw1       = w + 1600000;
    unsigned* hw2       = w + 3200000;
    unsigned* blockbase = w + 4800000;
    unsigned* rowptr    = w + 5000000;
    unsigned* bktcnt    = w + 5100004;
    unsigned* bktbase   = w + 5100500;
    float*    dinv      = (float*)(w + 5101000);
    float2*   headw     = (float2*)(w + 5201000);

    // CSR build: bucketed counting sort, no global data atomics
    hipMemsetAsync(bktcnt, 0, NBK * sizeof(unsigned), stream);
    k_p1<<<NBLK, 256, 0, stream>>>(dst, bktcnt, blockbase);
    k_p2<<<1, 512, 0, stream>>>(bktcnt, bktbase, rowptr);
    k_p3<<<NBLK, 256, 0, stream>>>(src, dst, bktbase, blockbase, edat);
    k_p4<<<NBK, 256, 0, stream>>>(edat, bktbase, rowptr, dinv);

    // conv1 transform -> bf16 table (pre-scaled by dinv)
    k_mm128<<<(NN + 255) / 256, 256, 0, stream>>>(x, W1, dinv, hw1);
    // conv1 aggregate + fused conv2 transform -> bf16 table
    k_gather<1><<<NN * HD / 256, 256, 0, stream>>>(edat, rowptr, dinv,
                                                   (const unsigned short*)hw1, b1, Wh, nullptr,
                                                   (unsigned short*)hw2, nullptr);
    // conv2 aggregate + fused heads -> headw (f32)
    k_gather<2><<<NN * HD / 256, 256, 0, stream>>>(edat, rowptr, dinv,
                                                   (const unsigned short*)hw2, bh, W2, Wsp,
                                                   nullptr, headw);
    // head aggregation -> outputs
    k_gscal<<<NN * HD / 256, 256, 0, stream>>>(edat, rowptr, dinv, headw, b2, bs, out);
}